// Round 1
// baseline (240.448 us; speedup 1.0000x reference)
//
#include <hip/hip_runtime.h>

// -------------------------------------------------------------------------
// GCN: h1 = relu(Agg(x@W1)+b1); h2 = relu(Agg(h1@W2)+b2); out = h2@Wl+bl
// R13 (from 235us best):
//   - gemm3: SWAPPED-OPERAND MFMA (acc holds C^T layout: lane=C-row,
//     regs=4 consecutive C-cols) -> epilogue is 16x 8B packed stores
//     instead of 64x 2B scalar stores. Stage only Bhi in LDS (32KB);
//     stream Blo from global (32KB, L1/L2-hot).
//   - k_agg: 16 edges in flight (4 gathers/lane/iter); self-row / bias /
//     dinv loads hoisted above the gather loop.
//   - edges array is u16 (N=50000 < 65536): halves place scatter + agg
//     index traffic.
// Carried mechanisms (counter-verified in prior session):
//   - bf16x3-split MFMA (hi*hi+hi*lo+lo*hi), XOR-swizzled LDS B, A frags
//     prefetched, dinv row-scaling fused into gemm epilogue.
//   - CSR build: rank captured from count's atomicAdd; place atomic-free.
//   - Failed & reverted: grid software barrier, XCD sharding, fat-kernel
//     overlap (aux inherits big LDS), merged scan.
// -------------------------------------------------------------------------

typedef __attribute__((ext_vector_type(8))) __bf16 bf16x8;
typedef __attribute__((ext_vector_type(8))) short short8;
typedef __attribute__((ext_vector_type(4))) float f32x4;

__device__ inline float bf_lo(unsigned u) { return __uint_as_float(u << 16); }
__device__ inline float bf_hi(unsigned u) { return __uint_as_float(u & 0xffff0000u); }
__device__ inline unsigned short f2bf(float v) {
  return __builtin_bit_cast(unsigned short, (__bf16)v);
}

// count in-degrees AND capture per-edge rank (old count value)
__global__ void k_count(const int* __restrict__ dst, int E,
                        int* __restrict__ cnt, int* __restrict__ rank) {
  int i = blockIdx.x * blockDim.x + threadIdx.x;
  if (i < E) rank[i] = atomicAdd(&cnt[dst[i]], 1);
}

// fat kernel: blocks [0, nb) do scan1 partials; [nb, nb+160) prepW
__global__ void k_scan1_prepW(const int* __restrict__ cnt, int n, int* __restrict__ partial,
                              int nb,
                              const float* __restrict__ W1, const float* __restrict__ W2,
                              const float* __restrict__ Wl,
                              unsigned short* __restrict__ b1h, unsigned short* __restrict__ b1l,
                              unsigned short* __restrict__ b2h, unsigned short* __restrict__ b2l,
                              unsigned short* __restrict__ blh, unsigned short* __restrict__ bll) {
  if ((int)blockIdx.x < nb) {
    __shared__ int s[256];
    int i = blockIdx.x * 256 + threadIdx.x;
    s[threadIdx.x] = (i < n) ? cnt[i] : 0;
    __syncthreads();
    for (int off = 128; off > 0; off >>= 1) {
      if (threadIdx.x < off) s[threadIdx.x] += s[threadIdx.x + off];
      __syncthreads();
    }
    if (threadIdx.x == 0) partial[blockIdx.x] = s[0];
  } else {
    int idx = ((int)blockIdx.x - nb) * 256 + threadIdx.x;
    const float* W;
    unsigned short *bh, *bl_;
    int N, local;
    if (idx < 16384)      { W = W1; bh = b1h; bl_ = b1l; N = 128; local = idx; }
    else if (idx < 32768) { W = W2; bh = b2h; bl_ = b2l; N = 128; local = idx - 16384; }
    else if (idx < 40960) { W = Wl; bh = blh; bl_ = bll; N = 64;  local = idx - 32768; }
    else return;
    int nn = local >> 7, k = local & 127;
    float v = W[(size_t)k * N + nn];
    __bf16 h = (__bf16)v;
    bh[local] = __builtin_bit_cast(unsigned short, h);
    bl_[local] = f2bf(v - (float)h);
  }
}

// scan3: block base from partials + exclusive scan -> row_off, dinv
__global__ void k_scan3(const int* __restrict__ cnt, const int* __restrict__ partial,
                        int nb, int n, int* __restrict__ row_off,
                        float* __restrict__ dinv) {
  __shared__ int s[256];
  __shared__ int base_s;
  int t = threadIdx.x;
  s[t] = (t < nb && t < (int)blockIdx.x) ? partial[t] : 0;
  __syncthreads();
  for (int off = 128; off > 0; off >>= 1) {
    if (t < off) s[t] += s[t + off];
    __syncthreads();
  }
  if (t == 0) base_s = s[0];
  __syncthreads();
  int base = base_s;
  __syncthreads();

  int i = blockIdx.x * 256 + t;
  int v = (i < n) ? cnt[i] : 0;
  s[t] = v;
  __syncthreads();
  for (int off = 1; off < 256; off <<= 1) {
    int u = (t >= off) ? s[t - off] : 0;
    __syncthreads();
    s[t] += u;
    __syncthreads();
  }
  int incl = s[t];
  int excl = incl - v;
  if (i < n) {
    row_off[i] = base + excl;
    dinv[i] = rsqrtf((float)(v + 1));
    if (i == n - 1) row_off[n] = base + incl;
  }
}

// place: NO atomics -- pos = row_off[dst] + rank; edges stored as u16
__global__ void k_place(const int* __restrict__ src, const int* __restrict__ dst,
                        const int* __restrict__ rank, const int* __restrict__ row_off,
                        int E, unsigned short* __restrict__ edges) {
  int e = blockIdx.x * blockDim.x + threadIdx.x;
  if (e < E) {
    int d = dst[e];
    int pos = row_off[d] + rank[e];
    __builtin_nontemporal_store((unsigned short)src[e], &edges[pos]);
  }
}

// ------------------- MFMA GEMM: A prefetched, Bhi in LDS, Blo streamed ----
// C[M x N] = A[M x 128] @ B[128 x N], N = NT*16.
// Operand-SWAPPED mfma: acc = mfma(b_frag, a_frag, acc) computes C^T tile
// layout: per lane, C-row = m_base+mt*16+lm, C-cols = nt*16+lk*4+r (r=0..3)
// -> packed 8B/16B epilogue stores.
// SCALE: multiply output row r by dinv[r] and write zero row M (agg OOB).
template <int NT, bool A32, bool BIAS, bool OUT_BF16, bool SCALE>
__global__ __launch_bounds__(256) void gemm3(
    const void* __restrict__ Ahi_, const unsigned short* __restrict__ Alo,
    const unsigned short* __restrict__ Bhi, const unsigned short* __restrict__ Blo,
    const float* __restrict__ bias, const float* __restrict__ dinv,
    void* __restrict__ Cout, int M) {
  constexpr int K = 128;
  constexpr int NCOL = NT * 16;
  __shared__ alignas(16) unsigned short lbh[NCOL * K];
  int t = threadIdx.x;
  int lane = t & 63, wave = t >> 6;
  int lm = lane & 15, lk = lane >> 4;
  int m_base = blockIdx.x * 128 + wave * 32;
  const short8 zero8 = {0, 0, 0, 0, 0, 0, 0, 0};

  if (SCALE && blockIdx.x == 0 && t < 64) {   // zero row M for agg OOB lanes
    *(unsigned*)&((unsigned short*)Cout)[(size_t)M * NCOL + t * 2] = 0u;
  }

  // ---- phase 1: prefetch all A fragments ----
  bf16x8 ah[2][4], al[2][4];
  if (A32) {
    const float* Af = (const float*)Ahi_;
    float4 ra[2][4][2];
#pragma unroll
    for (int mt = 0; mt < 2; ++mt) {
      int row = m_base + mt * 16 + lm;
#pragma unroll
      for (int ks = 0; ks < 4; ++ks) {
        if (row < M) {
          ra[mt][ks][0] = *(const float4*)&Af[(size_t)row * K + ks * 32 + lk * 8];
          ra[mt][ks][1] = *(const float4*)&Af[(size_t)row * K + ks * 32 + lk * 8 + 4];
        } else {
          ra[mt][ks][0] = make_float4(0.f, 0.f, 0.f, 0.f);
          ra[mt][ks][1] = make_float4(0.f, 0.f, 0.f, 0.f);
        }
      }
    }
#pragma unroll
    for (int mt = 0; mt < 2; ++mt)
#pragma unroll
      for (int ks = 0; ks < 4; ++ks) {
        float av[8] = {ra[mt][ks][0].x, ra[mt][ks][0].y, ra[mt][ks][0].z, ra[mt][ks][0].w,
                       ra[mt][ks][1].x, ra[mt][ks][1].y, ra[mt][ks][1].z, ra[mt][ks][1].w};
#pragma unroll
        for (int j = 0; j < 8; ++j) {
          __bf16 h = (__bf16)av[j];
          ah[mt][ks][j] = h;
          al[mt][ks][j] = (__bf16)(av[j] - (float)h);
        }
      }
  } else {
    const unsigned short* Ahi = (const unsigned short*)Ahi_;
#pragma unroll
    for (int mt = 0; mt < 2; ++mt) {
      int row = m_base + mt * 16 + lm;
#pragma unroll
      for (int ks = 0; ks < 4; ++ks) {
        if (row < M) {
          ah[mt][ks] = *(const bf16x8*)&Ahi[(size_t)row * K + ks * 32 + lk * 8];
          al[mt][ks] = *(const bf16x8*)&Alo[(size_t)row * K + ks * 32 + lk * 8];
        } else {
          ah[mt][ks] = __builtin_bit_cast(bf16x8, zero8);
          al[mt][ks] = __builtin_bit_cast(bf16x8, zero8);
        }
      }
    }
  }

  // ---- phase 2: cooperative Bhi staging (XOR-swizzled 16B chunks) ----
  for (int c = t; c < NCOL * 16; c += 256) {
    int r = c >> 4, q = c & 15;
    int sq = q ^ (r & 15);
    *(short8*)&lbh[r * K + sq * 8] = *(const short8*)&Bhi[r * K + q * 8];
  }
  __syncthreads();

  // ---- phase 3: LDS (Bhi) + global-stream (Blo) + MFMA, swapped operands --
  f32x4 acc[2][NT] = {};
#pragma unroll
  for (int ks = 0; ks < 4; ++ks) {
    int chunk = ks * 4 + lk;
    bf16x8 bh[NT], bl[NT];
#pragma unroll
    for (int nt = 0; nt < NT; ++nt) {
      int r = nt * 16 + lm;
      bh[nt] = *(const bf16x8*)&lbh[r * K + (chunk ^ lm) * 8];
      bl[nt] = *(const bf16x8*)&Blo[(size_t)r * K + chunk * 8];
    }
#pragma unroll
    for (int mt = 0; mt < 2; ++mt)
#pragma unroll
      for (int nt = 0; nt < NT; ++nt) {
        acc[mt][nt] = __builtin_amdgcn_mfma_f32_16x16x32_bf16(bh[nt], ah[mt][ks], acc[mt][nt], 0, 0, 0);
        acc[mt][nt] = __builtin_amdgcn_mfma_f32_16x16x32_bf16(bl[nt], ah[mt][ks], acc[mt][nt], 0, 0, 0);
        acc[mt][nt] = __builtin_amdgcn_mfma_f32_16x16x32_bf16(bh[nt], al[mt][ks], acc[mt][nt], 0, 0, 0);
      }
  }

  // ---- epilogue (transposed acc): row = m_base+mt*16+lm, cols = nt*16+lk*4+r
#pragma unroll
  for (int mt = 0; mt < 2; ++mt) {
    int row = m_base + mt * 16 + lm;
    if (row < M) {
      float dr = SCALE ? dinv[row] : 1.f;
#pragma unroll
      for (int nt = 0; nt < NT; ++nt) {
        int col0 = nt * 16 + lk * 4;
        float v0 = acc[mt][nt][0], v1 = acc[mt][nt][1];
        float v2 = acc[mt][nt][2], v3 = acc[mt][nt][3];
        if (SCALE) { v0 *= dr; v1 *= dr; v2 *= dr; v3 *= dr; }
        if (BIAS) {
          float4 bb = *(const float4*)&bias[col0];
          v0 += bb.x; v1 += bb.y; v2 += bb.z; v3 += bb.w;
        }
        if (OUT_BF16) {
          unsigned p0 = (unsigned)f2bf(v0) | ((unsigned)f2bf(v1) << 16);
          unsigned p1 = (unsigned)f2bf(v2) | ((unsigned)f2bf(v3) << 16);
          uint2 pk = make_uint2(p0, p1);
          *(uint2*)&((unsigned short*)Cout)[(size_t)row * NCOL + col0] = pk;
        } else {
          float4 pk = make_float4(v0, v1, v2, v3);
          *(float4*)&((float*)Cout)[(size_t)row * NCOL + col0] = pk;
        }
      }
    }
  }
}

// ------------------- aggregation: 16 edges in flight, u16 edges ----------
// rows pre-scaled by dinv[src]; agg_i = dinv_i*(sum + self) + bias, relu.
// OOB edge slots read zero row M (index n).
__global__ __launch_bounds__(256) void k_agg(const unsigned short* __restrict__ t,
                      const int* __restrict__ row_off,
                      const unsigned short* __restrict__ edges,
                      const float* __restrict__ dinv, const float* __restrict__ bias,
                      unsigned short* __restrict__ ghi, unsigned short* __restrict__ glo,
                      int n) {
  int wave = threadIdx.x >> 6;
  int lane = threadIdx.x & 63;
  int g = lane >> 4;
  int fl = lane & 15;          // features fl*8 .. fl*8+7
  int node = blockIdx.x * 4 + wave;
  if (node >= n) return;
  int2 ro = *(const int2*)&row_off[node];
  int e0 = ro.x, e1 = ro.y;
  int last = e1 - 1;

  // hoisted epilogue loads: overlap with gather chain
  float di = dinv[node];
  uint4 sv = *(const uint4*)&t[(size_t)node * 128 + fl * 8];
  float4 bb0 = *(const float4*)&bias[fl * 8];
  float4 bb1 = *(const float4*)&bias[fl * 8 + 4];

  float acc[8] = {};
  for (int base = e0; base < e1; base += 16) {
    int i0 = base + g, i1 = i0 + 4, i2 = i0 + 8, i3 = i0 + 12;
    int s0 = edges[i0 < e1 ? i0 : last];
    int s1 = edges[i1 < e1 ? i1 : last];
    int s2 = edges[i2 < e1 ? i2 : last];
    int s3 = edges[i3 < e1 ? i3 : last];
    s0 = i0 < e1 ? s0 : n;     // zero row
    s1 = i1 < e1 ? s1 : n;
    s2 = i2 < e1 ? s2 : n;
    s3 = i3 < e1 ? s3 : n;
    uint4 u0 = *(const uint4*)&t[(size_t)s0 * 128 + fl * 8];
    uint4 u1 = *(const uint4*)&t[(size_t)s1 * 128 + fl * 8];
    uint4 u2 = *(const uint4*)&t[(size_t)s2 * 128 + fl * 8];
    uint4 u3 = *(const uint4*)&t[(size_t)s3 * 128 + fl * 8];
    acc[0] += (bf_lo(u0.x) + bf_lo(u1.x)) + (bf_lo(u2.x) + bf_lo(u3.x));
    acc[1] += (bf_hi(u0.x) + bf_hi(u1.x)) + (bf_hi(u2.x) + bf_hi(u3.x));
    acc[2] += (bf_lo(u0.y) + bf_lo(u1.y)) + (bf_lo(u2.y) + bf_lo(u3.y));
    acc[3] += (bf_hi(u0.y) + bf_hi(u1.y)) + (bf_hi(u2.y) + bf_hi(u3.y));
    acc[4] += (bf_lo(u0.z) + bf_lo(u1.z)) + (bf_lo(u2.z) + bf_lo(u3.z));
    acc[5] += (bf_hi(u0.z) + bf_hi(u1.z)) + (bf_hi(u2.z) + bf_hi(u3.z));
    acc[6] += (bf_lo(u0.w) + bf_lo(u1.w)) + (bf_lo(u2.w) + bf_lo(u3.w));
    acc[7] += (bf_hi(u0.w) + bf_hi(u1.w)) + (bf_hi(u2.w) + bf_hi(u3.w));
  }
#pragma unroll
  for (int j = 0; j < 8; ++j) {
    acc[j] += __shfl_xor(acc[j], 16);
    acc[j] += __shfl_xor(acc[j], 32);
  }
  if (g == 0) {
    acc[0] += bf_lo(sv.x); acc[1] += bf_hi(sv.x);
    acc[2] += bf_lo(sv.y); acc[3] += bf_hi(sv.y);
    acc[4] += bf_lo(sv.z); acc[5] += bf_hi(sv.z);
    acc[6] += bf_lo(sv.w); acc[7] += bf_hi(sv.w);
    float bb[8] = {bb0.x, bb0.y, bb0.z, bb0.w, bb1.x, bb1.y, bb1.z, bb1.w};
    short8 ho, lo_;
#pragma unroll
    for (int j = 0; j < 8; ++j) {
      float s = fmaxf(acc[j] * di + bb[j], 0.f);
      __bf16 h = (__bf16)s;
      ho[j] = __builtin_bit_cast(short, h);
      lo_[j] = (short)f2bf(s - (float)h);
    }
    *(short8*)&ghi[(size_t)node * 128 + fl * 8] = ho;
    *(short8*)&glo[(size_t)node * 128 + fl * 8] = lo_;
  }
}

extern "C" void kernel_launch(void* const* d_in, const int* in_sizes, int n_in,
                              void* d_out, int out_size, void* d_ws, size_t ws_size,
                              hipStream_t stream) {
  const float* x  = (const float*)d_in[0];
  const int*   ei = (const int*)d_in[1];
  const float* W1 = (const float*)d_in[2];
  const float* b1 = (const float*)d_in[3];
  const float* W2 = (const float*)d_in[4];
  const float* b2 = (const float*)d_in[5];
  const float* Wl = (const float*)d_in[6];
  const float* bl = (const float*)d_in[7];
  float* out = (float*)d_out;

  const int D = 128;
  int N = in_sizes[0] / D;
  int E = in_sizes[1] / 2;
  const int* src = ei;
  const int* dst = ei + E;

  uintptr_t ws = (uintptr_t)d_ws;
  auto take = [&](size_t bytes) {
    uintptr_t p = ws;
    ws += (bytes + 15) & ~(size_t)15;
    return p;
  };
  unsigned short* t_bf = (unsigned short*)take(((size_t)N + 1) * D * 2);  // + zero row
  unsigned short* xh   = (unsigned short*)take((size_t)N * D * 2);
  unsigned short* xl   = (unsigned short*)take((size_t)N * D * 2);
  unsigned short* edges = (unsigned short*)take((size_t)E * 2);  // u16 src ids
  int*   rank    = (int*)take((size_t)E * 4);
  int*   cnt     = (int*)take((size_t)N * sizeof(int));
  int*   row_off = (int*)take(((size_t)N + 1) * sizeof(int));
  float* dinv    = (float*)take((size_t)N * sizeof(float));
  int*   partial = (int*)take(256 * sizeof(int));
  unsigned short* b1h = (unsigned short*)take(128 * 128 * 2);
  unsigned short* b1l = (unsigned short*)take(128 * 128 * 2);
  unsigned short* b2h = (unsigned short*)take(128 * 128 * 2);
  unsigned short* b2l = (unsigned short*)take(128 * 128 * 2);
  unsigned short* blh = (unsigned short*)take(128 * 64 * 2);
  unsigned short* bll = (unsigned short*)take(128 * 64 * 2);

  int nb_n = (N + 255) / 256;   // 196 (fits single-block base reduce)
  int nb_e = (E + 255) / 256;

  // ---- graph preprocessing + weight prep ----
  hipMemsetAsync(cnt, 0, (size_t)N * sizeof(int), stream);
  k_count<<<nb_e, 256, 0, stream>>>(dst, E, cnt, rank);
  k_scan1_prepW<<<nb_n + 160, 256, 0, stream>>>(cnt, N, partial, nb_n,
                                                W1, W2, Wl, b1h, b1l, b2h, b2l, blh, bll);
  k_scan3<<<nb_n, 256, 0, stream>>>(cnt, partial, nb_n, N, row_off, dinv);
  k_place<<<nb_e, 256, 0, stream>>>(src, dst, rank, row_off, E, edges);

  int gemm_blocks = (N + 127) / 128;
  int agg_blocks = (N + 3) / 4;

  // ---- layer 1 (A = fp32 x, split in-register; output pre-scaled by dinv) ----
  gemm3<8, true, false, true, true><<<gemm_blocks, 256, 0, stream>>>(
      x, nullptr, b1h, b1l, nullptr, dinv, t_bf, N);
  k_agg<<<agg_blocks, 256, 0, stream>>>(t_bf, row_off, edges, dinv, b1, xh, xl, N);
  // ---- layer 2 ----
  gemm3<8, false, false, true, true><<<gemm_blocks, 256, 0, stream>>>(
      xh, xl, b2h, b2l, nullptr, dinv, t_bf, N);
  k_agg<<<agg_blocks, 256, 0, stream>>>(t_bf, row_off, edges, dinv, b2, xh, xl, N);
  // ---- classifier ----
  gemm3<4, false, true, false, false><<<gemm_blocks, 256, 0, stream>>>(
      xh, xl, blh, bll, bl, nullptr, out, N);
}

// Round 3
// 230.950 us; speedup vs baseline: 1.0411x; 1.0411x over previous
//
#include <hip/hip_runtime.h>

// -------------------------------------------------------------------------
// GCN: h1 = relu(Agg(x@W1)+b1); h2 = relu(Agg(h1@W2)+b2); out = h2@Wl+bl
// R15 = R14 resubmitted verbatim (R14 bench was an infra flake: "container
// failed twice", no kernel-level evidence of failure).
// R14 (post-mortem of R13's 240us regression vs 235us best):
//   - REVERTED: Blo global-streaming in gemm3 MFMA loop (put ~200cyc L2
//     loads on the MFMA critical path at ~2 blocks/CU occupancy; LDS
//     ds_read_b128 is ~12cyc). Both Bhi and Blo staged in LDS again (64KB).
//   - KEPT from R13: swapped-operand MFMA (acc = mfma(b,a,acc) holds C^T
//     layout: lane=C-row, regs=4 consecutive C-cols -> packed 8B/16B
//     epilogue stores instead of 64x 2B scalar stores); u16 edges; 16-edge
//     agg unroll with hoisted epilogue loads.
//   - NEW: prepW fused into k_count (one fewer dispatch); dinv computed in
//     scan1 (already reads cnt).
// Carried mechanisms (counter-verified in prior session):
//   - bf16x3-split MFMA (hi*hi+hi*lo+lo*hi), XOR-swizzled LDS B, A frags
//     prefetched, dinv row-scaling fused into gemm epilogue.
//   - CSR build: rank captured from count's atomicAdd; place atomic-free.
//   - Failed & reverted: grid software barrier, XCD sharding, fat-kernel
//     overlap w/ big-LDS aux, merged scan, Blo global-streaming (R13).
// -------------------------------------------------------------------------

typedef __attribute__((ext_vector_type(8))) __bf16 bf16x8;
typedef __attribute__((ext_vector_type(8))) short short8;
typedef __attribute__((ext_vector_type(4))) float f32x4;

__device__ inline float bf_lo(unsigned u) { return __uint_as_float(u << 16); }
__device__ inline float bf_hi(unsigned u) { return __uint_as_float(u & 0xffff0000u); }
__device__ inline unsigned short f2bf(float v) {
  return __builtin_bit_cast(unsigned short, (__bf16)v);
}

// fat kernel: blocks [0, nbe) count in-degrees + capture rank;
// blocks [nbe, nbe+160) split/transpose weights to bf16 hi/lo
__global__ void k_count_prepW(const int* __restrict__ dst, int E, int nbe,
                              int* __restrict__ cnt, int* __restrict__ rank,
                              const float* __restrict__ W1, const float* __restrict__ W2,
                              const float* __restrict__ Wl,
                              unsigned short* __restrict__ b1h, unsigned short* __restrict__ b1l,
                              unsigned short* __restrict__ b2h, unsigned short* __restrict__ b2l,
                              unsigned short* __restrict__ blh, unsigned short* __restrict__ bll) {
  if ((int)blockIdx.x < nbe) {
    int i = blockIdx.x * 256 + threadIdx.x;
    if (i < E) rank[i] = atomicAdd(&cnt[dst[i]], 1);
  } else {
    int idx = ((int)blockIdx.x - nbe) * 256 + threadIdx.x;
    const float* W;
    unsigned short *bh, *bl_;
    int N, local;
    if (idx < 16384)      { W = W1; bh = b1h; bl_ = b1l; N = 128; local = idx; }
    else if (idx < 32768) { W = W2; bh = b2h; bl_ = b2l; N = 128; local = idx - 16384; }
    else if (idx < 40960) { W = Wl; bh = blh; bl_ = bll; N = 64;  local = idx - 32768; }
    else return;
    int nn = local >> 7, k = local & 127;
    float v = W[(size_t)k * N + nn];
    __bf16 h = (__bf16)v;
    bh[local] = __builtin_bit_cast(unsigned short, h);
    bl_[local] = f2bf(v - (float)h);
  }
}

// scan1: per-block partial sums of cnt; also dinv = rsqrt(deg+1)
__global__ void k_scan1(const int* __restrict__ cnt, int n, int* __restrict__ partial,
                        float* __restrict__ dinv) {
  __shared__ int s[256];
  int i = blockIdx.x * 256 + threadIdx.x;
  int v = (i < n) ? cnt[i] : 0;
  s[threadIdx.x] = v;
  if (i < n) dinv[i] = rsqrtf((float)(v + 1));
  __syncthreads();
  for (int off = 128; off > 0; off >>= 1) {
    if (threadIdx.x < off) s[threadIdx.x] += s[threadIdx.x + off];
    __syncthreads();
  }
  if (threadIdx.x == 0) partial[blockIdx.x] = s[0];
}

// scan3: block base from partials + exclusive scan -> row_off
__global__ void k_scan3(const int* __restrict__ cnt, const int* __restrict__ partial,
                        int nb, int n, int* __restrict__ row_off) {
  __shared__ int s[256];
  __shared__ int base_s;
  int t = threadIdx.x;
  s[t] = (t < nb && t < (int)blockIdx.x) ? partial[t] : 0;
  __syncthreads();
  for (int off = 128; off > 0; off >>= 1) {
    if (t < off) s[t] += s[t + off];
    __syncthreads();
  }
  if (t == 0) base_s = s[0];
  __syncthreads();
  int base = base_s;
  __syncthreads();

  int i = blockIdx.x * 256 + t;
  int v = (i < n) ? cnt[i] : 0;
  s[t] = v;
  __syncthreads();
  for (int off = 1; off < 256; off <<= 1) {
    int u = (t >= off) ? s[t - off] : 0;
    __syncthreads();
    s[t] += u;
    __syncthreads();
  }
  int incl = s[t];
  int excl = incl - v;
  if (i < n) {
    row_off[i] = base + excl;
    if (i == n - 1) row_off[n] = base + incl;
  }
}

// place: NO atomics -- pos = row_off[dst] + rank; edges stored as u16
__global__ void k_place(const int* __restrict__ src, const int* __restrict__ dst,
                        const int* __restrict__ rank, const int* __restrict__ row_off,
                        int E, unsigned short* __restrict__ edges) {
  int e = blockIdx.x * blockDim.x + threadIdx.x;
  if (e < E) {
    int d = dst[e];
    int pos = row_off[d] + rank[e];
    __builtin_nontemporal_store((unsigned short)src[e], &edges[pos]);
  }
}

// ------------------- MFMA GEMM: A prefetched, B (hi+lo) in LDS -----------
// C[M x N] = A[M x 128] @ B[128 x N], N = NT*16.
// Operand-SWAPPED mfma: acc = mfma(b_frag, a_frag, acc) computes C^T tile
// layout: per lane, C-row = m_base+mt*16+lm, C-cols = nt*16+lk*4+r (r=0..3)
// -> packed 8B/16B epilogue stores.
// SCALE: multiply output row r by dinv[r] and write zero row M (agg OOB).
template <int NT, bool A32, bool BIAS, bool OUT_BF16, bool SCALE>
__global__ __launch_bounds__(256) void gemm3(
    const void* __restrict__ Ahi_, const unsigned short* __restrict__ Alo,
    const unsigned short* __restrict__ Bhi, const unsigned short* __restrict__ Blo,
    const float* __restrict__ bias, const float* __restrict__ dinv,
    void* __restrict__ Cout, int M) {
  constexpr int K = 128;
  constexpr int NCOL = NT * 16;
  __shared__ alignas(16) unsigned short lbh[NCOL * K];
  __shared__ alignas(16) unsigned short lbl[NCOL * K];
  int t = threadIdx.x;
  int lane = t & 63, wave = t >> 6;
  int lm = lane & 15, lk = lane >> 4;
  int m_base = blockIdx.x * 128 + wave * 32;
  const short8 zero8 = {0, 0, 0, 0, 0, 0, 0, 0};

  if (SCALE && blockIdx.x == 0 && t < 64) {   // zero row M for agg OOB lanes
    *(unsigned*)&((unsigned short*)Cout)[(size_t)M * NCOL + t * 2] = 0u;
  }

  // ---- phase 1: prefetch all A fragments ----
  bf16x8 ah[2][4], al[2][4];
  if (A32) {
    const float* Af = (const float*)Ahi_;
    float4 ra[2][4][2];
#pragma unroll
    for (int mt = 0; mt < 2; ++mt) {
      int row = m_base + mt * 16 + lm;
#pragma unroll
      for (int ks = 0; ks < 4; ++ks) {
        if (row < M) {
          ra[mt][ks][0] = *(const float4*)&Af[(size_t)row * K + ks * 32 + lk * 8];
          ra[mt][ks][1] = *(const float4*)&Af[(size_t)row * K + ks * 32 + lk * 8 + 4];
        } else {
          ra[mt][ks][0] = make_float4(0.f, 0.f, 0.f, 0.f);
          ra[mt][ks][1] = make_float4(0.f, 0.f, 0.f, 0.f);
        }
      }
    }
#pragma unroll
    for (int mt = 0; mt < 2; ++mt)
#pragma unroll
      for (int ks = 0; ks < 4; ++ks) {
        float av[8] = {ra[mt][ks][0].x, ra[mt][ks][0].y, ra[mt][ks][0].z, ra[mt][ks][0].w,
                       ra[mt][ks][1].x, ra[mt][ks][1].y, ra[mt][ks][1].z, ra[mt][ks][1].w};
#pragma unroll
        for (int j = 0; j < 8; ++j) {
          __bf16 h = (__bf16)av[j];
          ah[mt][ks][j] = h;
          al[mt][ks][j] = (__bf16)(av[j] - (float)h);
        }
      }
  } else {
    const unsigned short* Ahi = (const unsigned short*)Ahi_;
#pragma unroll
    for (int mt = 0; mt < 2; ++mt) {
      int row = m_base + mt * 16 + lm;
#pragma unroll
      for (int ks = 0; ks < 4; ++ks) {
        if (row < M) {
          ah[mt][ks] = *(const bf16x8*)&Ahi[(size_t)row * K + ks * 32 + lk * 8];
          al[mt][ks] = *(const bf16x8*)&Alo[(size_t)row * K + ks * 32 + lk * 8];
        } else {
          ah[mt][ks] = __builtin_bit_cast(bf16x8, zero8);
          al[mt][ks] = __builtin_bit_cast(bf16x8, zero8);
        }
      }
    }
  }

  // ---- phase 2: cooperative B staging (XOR-swizzled 16B chunks) ----
  for (int c = t; c < NCOL * 16; c += 256) {
    int r = c >> 4, q = c & 15;
    int sq = q ^ (r & 15);
    *(short8*)&lbh[r * K + sq * 8] = *(const short8*)&Bhi[r * K + q * 8];
    *(short8*)&lbl[r * K + sq * 8] = *(const short8*)&Blo[r * K + q * 8];
  }
  __syncthreads();

  // ---- phase 3: pure LDS + MFMA, swapped operands ----
  f32x4 acc[2][NT] = {};
#pragma unroll
  for (int ks = 0; ks < 4; ++ks) {
    int chunk = ks * 4 + lk;
    bf16x8 bh[NT], bl[NT];
#pragma unroll
    for (int nt = 0; nt < NT; ++nt) {
      int r = nt * 16 + lm;
      int sq = chunk ^ lm;
      bh[nt] = *(const bf16x8*)&lbh[r * K + sq * 8];
      bl[nt] = *(const bf16x8*)&lbl[r * K + sq * 8];
    }
#pragma unroll
    for (int mt = 0; mt < 2; ++mt)
#pragma unroll
      for (int nt = 0; nt < NT; ++nt) {
        acc[mt][nt] = __builtin_amdgcn_mfma_f32_16x16x32_bf16(bh[nt], ah[mt][ks], acc[mt][nt], 0, 0, 0);
        acc[mt][nt] = __builtin_amdgcn_mfma_f32_16x16x32_bf16(bl[nt], ah[mt][ks], acc[mt][nt], 0, 0, 0);
        acc[mt][nt] = __builtin_amdgcn_mfma_f32_16x16x32_bf16(bh[nt], al[mt][ks], acc[mt][nt], 0, 0, 0);
      }
  }

  // ---- epilogue (transposed acc): row = m_base+mt*16+lm, cols = nt*16+lk*4+r
#pragma unroll
  for (int mt = 0; mt < 2; ++mt) {
    int row = m_base + mt * 16 + lm;
    if (row < M) {
      float dr = SCALE ? dinv[row] : 1.f;
#pragma unroll
      for (int nt = 0; nt < NT; ++nt) {
        int col0 = nt * 16 + lk * 4;
        float v0 = acc[mt][nt][0], v1 = acc[mt][nt][1];
        float v2 = acc[mt][nt][2], v3 = acc[mt][nt][3];
        if (SCALE) { v0 *= dr; v1 *= dr; v2 *= dr; v3 *= dr; }
        if (BIAS) {
          float4 bb = *(const float4*)&bias[col0];
          v0 += bb.x; v1 += bb.y; v2 += bb.z; v3 += bb.w;
        }
        if (OUT_BF16) {
          unsigned p0 = (unsigned)f2bf(v0) | ((unsigned)f2bf(v1) << 16);
          unsigned p1 = (unsigned)f2bf(v2) | ((unsigned)f2bf(v3) << 16);
          uint2 pk = make_uint2(p0, p1);
          *(uint2*)&((unsigned short*)Cout)[(size_t)row * NCOL + col0] = pk;
        } else {
          float4 pk = make_float4(v0, v1, v2, v3);
          *(float4*)&((float*)Cout)[(size_t)row * NCOL + col0] = pk;
        }
      }
    }
  }
}

// ------------------- aggregation: 16 edges in flight, u16 edges ----------
// rows pre-scaled by dinv[src]; agg_i = dinv_i*(sum + self) + bias, relu.
// OOB edge slots read zero row M (index n).
__global__ __launch_bounds__(256) void k_agg(const unsigned short* __restrict__ t,
                      const int* __restrict__ row_off,
                      const unsigned short* __restrict__ edges,
                      const float* __restrict__ dinv, const float* __restrict__ bias,
                      unsigned short* __restrict__ ghi, unsigned short* __restrict__ glo,
                      int n) {
  int wave = threadIdx.x >> 6;
  int lane = threadIdx.x & 63;
  int g = lane >> 4;
  int fl = lane & 15;          // features fl*8 .. fl*8+7
  int node = blockIdx.x * 4 + wave;
  if (node >= n) return;
  int2 ro = *(const int2*)&row_off[node];
  int e0 = ro.x, e1 = ro.y;
  int last = e1 - 1;

  // hoisted epilogue loads: overlap with gather chain
  float di = dinv[node];
  uint4 sv = *(const uint4*)&t[(size_t)node * 128 + fl * 8];
  float4 bb0 = *(const float4*)&bias[fl * 8];
  float4 bb1 = *(const float4*)&bias[fl * 8 + 4];

  float acc[8] = {};
  for (int base = e0; base < e1; base += 16) {
    int i0 = base + g, i1 = i0 + 4, i2 = i0 + 8, i3 = i0 + 12;
    int s0 = edges[i0 < e1 ? i0 : last];
    int s1 = edges[i1 < e1 ? i1 : last];
    int s2 = edges[i2 < e1 ? i2 : last];
    int s3 = edges[i3 < e1 ? i3 : last];
    s0 = i0 < e1 ? s0 : n;     // zero row
    s1 = i1 < e1 ? s1 : n;
    s2 = i2 < e1 ? s2 : n;
    s3 = i3 < e1 ? s3 : n;
    uint4 u0 = *(const uint4*)&t[(size_t)s0 * 128 + fl * 8];
    uint4 u1 = *(const uint4*)&t[(size_t)s1 * 128 + fl * 8];
    uint4 u2 = *(const uint4*)&t[(size_t)s2 * 128 + fl * 8];
    uint4 u3 = *(const uint4*)&t[(size_t)s3 * 128 + fl * 8];
    acc[0] += (bf_lo(u0.x) + bf_lo(u1.x)) + (bf_lo(u2.x) + bf_lo(u3.x));
    acc[1] += (bf_hi(u0.x) + bf_hi(u1.x)) + (bf_hi(u2.x) + bf_hi(u3.x));
    acc[2] += (bf_lo(u0.y) + bf_lo(u1.y)) + (bf_lo(u2.y) + bf_lo(u3.y));
    acc[3] += (bf_hi(u0.y) + bf_hi(u1.y)) + (bf_hi(u2.y) + bf_hi(u3.y));
    acc[4] += (bf_lo(u0.z) + bf_lo(u1.z)) + (bf_lo(u2.z) + bf_lo(u3.z));
    acc[5] += (bf_hi(u0.z) + bf_hi(u1.z)) + (bf_hi(u2.z) + bf_hi(u3.z));
    acc[6] += (bf_lo(u0.w) + bf_lo(u1.w)) + (bf_lo(u2.w) + bf_lo(u3.w));
    acc[7] += (bf_hi(u0.w) + bf_hi(u1.w)) + (bf_hi(u2.w) + bf_hi(u3.w));
  }
#pragma unroll
  for (int j = 0; j < 8; ++j) {
    acc[j] += __shfl_xor(acc[j], 16);
    acc[j] += __shfl_xor(acc[j], 32);
  }
  if (g == 0) {
    acc[0] += bf_lo(sv.x); acc[1] += bf_hi(sv.x);
    acc[2] += bf_lo(sv.y); acc[3] += bf_hi(sv.y);
    acc[4] += bf_lo(sv.z); acc[5] += bf_hi(sv.z);
    acc[6] += bf_lo(sv.w); acc[7] += bf_hi(sv.w);
    float bb[8] = {bb0.x, bb0.y, bb0.z, bb0.w, bb1.x, bb1.y, bb1.z, bb1.w};
    short8 ho, lo_;
#pragma unroll
    for (int j = 0; j < 8; ++j) {
      float s = fmaxf(acc[j] * di + bb[j], 0.f);
      __bf16 h = (__bf16)s;
      ho[j] = __builtin_bit_cast(short, h);
      lo_[j] = (short)f2bf(s - (float)h);
    }
    *(short8*)&ghi[(size_t)node * 128 + fl * 8] = ho;
    *(short8*)&glo[(size_t)node * 128 + fl * 8] = lo_;
  }
}

extern "C" void kernel_launch(void* const* d_in, const int* in_sizes, int n_in,
                              void* d_out, int out_size, void* d_ws, size_t ws_size,
                              hipStream_t stream) {
  const float* x  = (const float*)d_in[0];
  const int*   ei = (const int*)d_in[1];
  const float* W1 = (const float*)d_in[2];
  const float* b1 = (const float*)d_in[3];
  const float* W2 = (const float*)d_in[4];
  const float* b2 = (const float*)d_in[5];
  const float* Wl = (const float*)d_in[6];
  const float* bl = (const float*)d_in[7];
  float* out = (float*)d_out;

  const int D = 128;
  int N = in_sizes[0] / D;
  int E = in_sizes[1] / 2;
  const int* src = ei;
  const int* dst = ei + E;

  uintptr_t ws = (uintptr_t)d_ws;
  auto take = [&](size_t bytes) {
    uintptr_t p = ws;
    ws += (bytes + 15) & ~(size_t)15;
    return p;
  };
  unsigned short* t_bf = (unsigned short*)take(((size_t)N + 1) * D * 2);  // + zero row
  unsigned short* xh   = (unsigned short*)take((size_t)N * D * 2);
  unsigned short* xl   = (unsigned short*)take((size_t)N * D * 2);
  unsigned short* edges = (unsigned short*)take((size_t)E * 2);  // u16 src ids
  int*   rank    = (int*)take((size_t)E * 4);
  int*   cnt     = (int*)take((size_t)N * sizeof(int));
  int*   row_off = (int*)take(((size_t)N + 1) * sizeof(int));
  float* dinv    = (float*)take((size_t)N * sizeof(float));
  int*   partial = (int*)take(256 * sizeof(int));
  unsigned short* b1h = (unsigned short*)take(128 * 128 * 2);
  unsigned short* b1l = (unsigned short*)take(128 * 128 * 2);
  unsigned short* b2h = (unsigned short*)take(128 * 128 * 2);
  unsigned short* b2l = (unsigned short*)take(128 * 128 * 2);
  unsigned short* blh = (unsigned short*)take(128 * 64 * 2);
  unsigned short* bll = (unsigned short*)take(128 * 64 * 2);

  int nb_n = (N + 255) / 256;   // 196 (fits single-block base reduce)
  int nb_e = (E + 255) / 256;

  // ---- graph preprocessing + weight prep ----
  hipMemsetAsync(cnt, 0, (size_t)N * sizeof(int), stream);
  k_count_prepW<<<nb_e + 160, 256, 0, stream>>>(dst, E, nb_e, cnt, rank,
                                                W1, W2, Wl, b1h, b1l, b2h, b2l, blh, bll);
  k_scan1<<<nb_n, 256, 0, stream>>>(cnt, N, partial, dinv);
  k_scan3<<<nb_n, 256, 0, stream>>>(cnt, partial, nb_n, N, row_off);
  k_place<<<nb_e, 256, 0, stream>>>(src, dst, rank, row_off, E, edges);

  int gemm_blocks = (N + 127) / 128;
  int agg_blocks = (N + 3) / 4;

  // ---- layer 1 (A = fp32 x, split in-register; output pre-scaled by dinv) ----
  gemm3<8, true, false, true, true><<<gemm_blocks, 256, 0, stream>>>(
      x, nullptr, b1h, b1l, nullptr, dinv, t_bf, N);
  k_agg<<<agg_blocks, 256, 0, stream>>>(t_bf, row_off, edges, dinv, b1, xh, xl, N);
  // ---- layer 2 ----
  gemm3<8, false, false, true, true><<<gemm_blocks, 256, 0, stream>>>(
      xh, xl, b2h, b2l, nullptr, dinv, t_bf, N);
  k_agg<<<agg_blocks, 256, 0, stream>>>(t_bf, row_off, edges, dinv, b2, xh, xl, N);
  // ---- classifier ----
  gemm3<4, false, true, false, false><<<gemm_blocks, 256, 0, stream>>>(
      xh, xl, blh, bll, bl, nullptr, out, N);
}

// Round 4
// 228.764 us; speedup vs baseline: 1.0511x; 1.0096x over previous
//
#include <hip/hip_runtime.h>

// -------------------------------------------------------------------------
// GCN: h1 = relu(Agg(x@W1)+b1); h2 = relu(Agg(h1@W2)+b2); out = h2@Wl+bl
// R16 (from R15's 230.9us best): agg-only change, designed as an ablation
// probe of the agg regime (VALU-bound vs L3-BW-bound):
//   - k_agg hot loop: accumulate in float2 via v_pk_add_f32 (VOP3P packed
//     math, inline asm). Per uint4 word: 2 extracts + 1 pk_add vs
//     2 extracts + 2 scalar adds -> hot-loop VALU 64->48 ops, acc dep
//     chain halved. Bit-identical arithmetic (same pairwise tree, fp32).
// R15/R14 (vs 235us): swapped-operand MFMA (acc = mfma(b,a,acc), C^T
//   layout: lane=C-row, regs=4 consecutive C-cols -> packed 8B/16B
//   epilogue stores); u16 edges; 16-edge agg unroll + hoisted epilogue
//   loads; prepW fused into k_count; dinv in scan1. Blo stays in LDS
//   (R13 lesson: global B on MFMA critical path at low occupancy = -5us).
// Carried mechanisms (counter-verified):
//   - bf16x3-split MFMA (hi*hi+hi*lo+lo*hi), XOR-swizzled LDS B, A frags
//     prefetched, dinv row-scaling fused into gemm epilogue.
//   - CSR build: rank captured from count's atomicAdd; place atomic-free.
//   - Failed & reverted: grid software barrier, XCD sharding, fat-kernel
//     overlap w/ big-LDS aux, merged scan, Blo global-streaming (R13).
// -------------------------------------------------------------------------

typedef __attribute__((ext_vector_type(8))) __bf16 bf16x8;
typedef __attribute__((ext_vector_type(8))) short short8;
typedef __attribute__((ext_vector_type(4))) float f32x4;
typedef __attribute__((ext_vector_type(2))) float f32x2;

__device__ inline float bf_lo(unsigned u) { return __uint_as_float(u << 16); }
__device__ inline float bf_hi(unsigned u) { return __uint_as_float(u & 0xffff0000u); }
__device__ inline unsigned short f2bf(float v) {
  return __builtin_bit_cast(unsigned short, (__bf16)v);
}
// packed 2xf32 add (VOP3P); pure VALU, no memory clobber so loads schedule
__device__ inline f32x2 pkadd(f32x2 a, f32x2 b) {
  f32x2 d;
  asm("v_pk_add_f32 %0, %1, %2" : "=v"(d) : "v"(a), "v"(b));
  return d;
}
// bf16 pair word -> float2 {low half, high half} (features 2j, 2j+1)
__device__ inline f32x2 bfpair(unsigned w) {
  f32x2 r;
  r.x = __uint_as_float(w << 16);
  r.y = __uint_as_float(w & 0xffff0000u);
  return r;
}

// fat kernel: blocks [0, nbe) count in-degrees + capture rank;
// blocks [nbe, nbe+160) split/transpose weights to bf16 hi/lo
__global__ void k_count_prepW(const int* __restrict__ dst, int E, int nbe,
                              int* __restrict__ cnt, int* __restrict__ rank,
                              const float* __restrict__ W1, const float* __restrict__ W2,
                              const float* __restrict__ Wl,
                              unsigned short* __restrict__ b1h, unsigned short* __restrict__ b1l,
                              unsigned short* __restrict__ b2h, unsigned short* __restrict__ b2l,
                              unsigned short* __restrict__ blh, unsigned short* __restrict__ bll) {
  if ((int)blockIdx.x < nbe) {
    int i = blockIdx.x * 256 + threadIdx.x;
    if (i < E) rank[i] = atomicAdd(&cnt[dst[i]], 1);
  } else {
    int idx = ((int)blockIdx.x - nbe) * 256 + threadIdx.x;
    const float* W;
    unsigned short *bh, *bl_;
    int N, local;
    if (idx < 16384)      { W = W1; bh = b1h; bl_ = b1l; N = 128; local = idx; }
    else if (idx < 32768) { W = W2; bh = b2h; bl_ = b2l; N = 128; local = idx - 16384; }
    else if (idx < 40960) { W = Wl; bh = blh; bl_ = bll; N = 64;  local = idx - 32768; }
    else return;
    int nn = local >> 7, k = local & 127;
    float v = W[(size_t)k * N + nn];
    __bf16 h = (__bf16)v;
    bh[local] = __builtin_bit_cast(unsigned short, h);
    bl_[local] = f2bf(v - (float)h);
  }
}

// scan1: per-block partial sums of cnt; also dinv = rsqrt(deg+1)
__global__ void k_scan1(const int* __restrict__ cnt, int n, int* __restrict__ partial,
                        float* __restrict__ dinv) {
  __shared__ int s[256];
  int i = blockIdx.x * 256 + threadIdx.x;
  int v = (i < n) ? cnt[i] : 0;
  s[threadIdx.x] = v;
  if (i < n) dinv[i] = rsqrtf((float)(v + 1));
  __syncthreads();
  for (int off = 128; off > 0; off >>= 1) {
    if (threadIdx.x < off) s[threadIdx.x] += s[threadIdx.x + off];
    __syncthreads();
  }
  if (threadIdx.x == 0) partial[blockIdx.x] = s[0];
}

// scan3: block base from partials + exclusive scan -> row_off
__global__ void k_scan3(const int* __restrict__ cnt, const int* __restrict__ partial,
                        int nb, int n, int* __restrict__ row_off) {
  __shared__ int s[256];
  __shared__ int base_s;
  int t = threadIdx.x;
  s[t] = (t < nb && t < (int)blockIdx.x) ? partial[t] : 0;
  __syncthreads();
  for (int off = 128; off > 0; off >>= 1) {
    if (t < off) s[t] += s[t + off];
    __syncthreads();
  }
  if (t == 0) base_s = s[0];
  __syncthreads();
  int base = base_s;
  __syncthreads();

  int i = blockIdx.x * 256 + t;
  int v = (i < n) ? cnt[i] : 0;
  s[t] = v;
  __syncthreads();
  for (int off = 1; off < 256; off <<= 1) {
    int u = (t >= off) ? s[t - off] : 0;
    __syncthreads();
    s[t] += u;
    __syncthreads();
  }
  int incl = s[t];
  int excl = incl - v;
  if (i < n) {
    row_off[i] = base + excl;
    if (i == n - 1) row_off[n] = base + incl;
  }
}

// place: NO atomics -- pos = row_off[dst] + rank; edges stored as u16
__global__ void k_place(const int* __restrict__ src, const int* __restrict__ dst,
                        const int* __restrict__ rank, const int* __restrict__ row_off,
                        int E, unsigned short* __restrict__ edges) {
  int e = blockIdx.x * blockDim.x + threadIdx.x;
  if (e < E) {
    int d = dst[e];
    int pos = row_off[d] + rank[e];
    __builtin_nontemporal_store((unsigned short)src[e], &edges[pos]);
  }
}

// ------------------- MFMA GEMM: A prefetched, B (hi+lo) in LDS -----------
// C[M x N] = A[M x 128] @ B[128 x N], N = NT*16.
// Operand-SWAPPED mfma: acc = mfma(b_frag, a_frag, acc) computes C^T tile
// layout: per lane, C-row = m_base+mt*16+lm, C-cols = nt*16+lk*4+r (r=0..3)
// -> packed 8B/16B epilogue stores.
// SCALE: multiply output row r by dinv[r] and write zero row M (agg OOB).
template <int NT, bool A32, bool BIAS, bool OUT_BF16, bool SCALE>
__global__ __launch_bounds__(256) void gemm3(
    const void* __restrict__ Ahi_, const unsigned short* __restrict__ Alo,
    const unsigned short* __restrict__ Bhi, const unsigned short* __restrict__ Blo,
    const float* __restrict__ bias, const float* __restrict__ dinv,
    void* __restrict__ Cout, int M) {
  constexpr int K = 128;
  constexpr int NCOL = NT * 16;
  __shared__ alignas(16) unsigned short lbh[NCOL * K];
  __shared__ alignas(16) unsigned short lbl[NCOL * K];
  int t = threadIdx.x;
  int lane = t & 63, wave = t >> 6;
  int lm = lane & 15, lk = lane >> 4;
  int m_base = blockIdx.x * 128 + wave * 32;
  const short8 zero8 = {0, 0, 0, 0, 0, 0, 0, 0};

  if (SCALE && blockIdx.x == 0 && t < 64) {   // zero row M for agg OOB lanes
    *(unsigned*)&((unsigned short*)Cout)[(size_t)M * NCOL + t * 2] = 0u;
  }

  // ---- phase 1: prefetch all A fragments ----
  bf16x8 ah[2][4], al[2][4];
  if (A32) {
    const float* Af = (const float*)Ahi_;
    float4 ra[2][4][2];
#pragma unroll
    for (int mt = 0; mt < 2; ++mt) {
      int row = m_base + mt * 16 + lm;
#pragma unroll
      for (int ks = 0; ks < 4; ++ks) {
        if (row < M) {
          ra[mt][ks][0] = *(const float4*)&Af[(size_t)row * K + ks * 32 + lk * 8];
          ra[mt][ks][1] = *(const float4*)&Af[(size_t)row * K + ks * 32 + lk * 8 + 4];
        } else {
          ra[mt][ks][0] = make_float4(0.f, 0.f, 0.f, 0.f);
          ra[mt][ks][1] = make_float4(0.f, 0.f, 0.f, 0.f);
        }
      }
    }
#pragma unroll
    for (int mt = 0; mt < 2; ++mt)
#pragma unroll
      for (int ks = 0; ks < 4; ++ks) {
        float av[8] = {ra[mt][ks][0].x, ra[mt][ks][0].y, ra[mt][ks][0].z, ra[mt][ks][0].w,
                       ra[mt][ks][1].x, ra[mt][ks][1].y, ra[mt][ks][1].z, ra[mt][ks][1].w};
#pragma unroll
        for (int j = 0; j < 8; ++j) {
          __bf16 h = (__bf16)av[j];
          ah[mt][ks][j] = h;
          al[mt][ks][j] = (__bf16)(av[j] - (float)h);
        }
      }
  } else {
    const unsigned short* Ahi = (const unsigned short*)Ahi_;
#pragma unroll
    for (int mt = 0; mt < 2; ++mt) {
      int row = m_base + mt * 16 + lm;
#pragma unroll
      for (int ks = 0; ks < 4; ++ks) {
        if (row < M) {
          ah[mt][ks] = *(const bf16x8*)&Ahi[(size_t)row * K + ks * 32 + lk * 8];
          al[mt][ks] = *(const bf16x8*)&Alo[(size_t)row * K + ks * 32 + lk * 8];
        } else {
          ah[mt][ks] = __builtin_bit_cast(bf16x8, zero8);
          al[mt][ks] = __builtin_bit_cast(bf16x8, zero8);
        }
      }
    }
  }

  // ---- phase 2: cooperative B staging (XOR-swizzled 16B chunks) ----
  for (int c = t; c < NCOL * 16; c += 256) {
    int r = c >> 4, q = c & 15;
    int sq = q ^ (r & 15);
    *(short8*)&lbh[r * K + sq * 8] = *(const short8*)&Bhi[r * K + q * 8];
    *(short8*)&lbl[r * K + sq * 8] = *(const short8*)&Blo[r * K + q * 8];
  }
  __syncthreads();

  // ---- phase 3: pure LDS + MFMA, swapped operands ----
  f32x4 acc[2][NT] = {};
#pragma unroll
  for (int ks = 0; ks < 4; ++ks) {
    int chunk = ks * 4 + lk;
    bf16x8 bh[NT], bl[NT];
#pragma unroll
    for (int nt = 0; nt < NT; ++nt) {
      int r = nt * 16 + lm;
      int sq = chunk ^ lm;
      bh[nt] = *(const bf16x8*)&lbh[r * K + sq * 8];
      bl[nt] = *(const bf16x8*)&lbl[r * K + sq * 8];
    }
#pragma unroll
    for (int mt = 0; mt < 2; ++mt)
#pragma unroll
      for (int nt = 0; nt < NT; ++nt) {
        acc[mt][nt] = __builtin_amdgcn_mfma_f32_16x16x32_bf16(bh[nt], ah[mt][ks], acc[mt][nt], 0, 0, 0);
        acc[mt][nt] = __builtin_amdgcn_mfma_f32_16x16x32_bf16(bl[nt], ah[mt][ks], acc[mt][nt], 0, 0, 0);
        acc[mt][nt] = __builtin_amdgcn_mfma_f32_16x16x32_bf16(bh[nt], al[mt][ks], acc[mt][nt], 0, 0, 0);
      }
  }

  // ---- epilogue (transposed acc): row = m_base+mt*16+lm, cols = nt*16+lk*4+r
#pragma unroll
  for (int mt = 0; mt < 2; ++mt) {
    int row = m_base + mt * 16 + lm;
    if (row < M) {
      float dr = SCALE ? dinv[row] : 1.f;
#pragma unroll
      for (int nt = 0; nt < NT; ++nt) {
        int col0 = nt * 16 + lk * 4;
        float v0 = acc[mt][nt][0], v1 = acc[mt][nt][1];
        float v2 = acc[mt][nt][2], v3 = acc[mt][nt][3];
        if (SCALE) { v0 *= dr; v1 *= dr; v2 *= dr; v3 *= dr; }
        if (BIAS) {
          float4 bb = *(const float4*)&bias[col0];
          v0 += bb.x; v1 += bb.y; v2 += bb.z; v3 += bb.w;
        }
        if (OUT_BF16) {
          unsigned p0 = (unsigned)f2bf(v0) | ((unsigned)f2bf(v1) << 16);
          unsigned p1 = (unsigned)f2bf(v2) | ((unsigned)f2bf(v3) << 16);
          uint2 pk = make_uint2(p0, p1);
          *(uint2*)&((unsigned short*)Cout)[(size_t)row * NCOL + col0] = pk;
        } else {
          float4 pk = make_float4(v0, v1, v2, v3);
          *(float4*)&((float*)Cout)[(size_t)row * NCOL + col0] = pk;
        }
      }
    }
  }
}

// ------------------- aggregation: 16 edges in flight, u16 edges ----------
// rows pre-scaled by dinv[src]; agg_i = dinv_i*(sum + self) + bias, relu.
// OOB edge slots read zero row M (index n).
// Hot loop accumulates in float2 via v_pk_add_f32: 48 VALU/iter vs 64
// scalar, halved acc dependence chain. Bit-identical pairwise-tree fp32.
__global__ __launch_bounds__(256) void k_agg(const unsigned short* __restrict__ t,
                      const int* __restrict__ row_off,
                      const unsigned short* __restrict__ edges,
                      const float* __restrict__ dinv, const float* __restrict__ bias,
                      unsigned short* __restrict__ ghi, unsigned short* __restrict__ glo,
                      int n) {
  int wave = threadIdx.x >> 6;
  int lane = threadIdx.x & 63;
  int g = lane >> 4;
  int fl = lane & 15;          // features fl*8 .. fl*8+7
  int node = blockIdx.x * 4 + wave;
  if (node >= n) return;
  int2 ro = *(const int2*)&row_off[node];
  int e0 = ro.x, e1 = ro.y;
  int last = e1 - 1;

  // hoisted epilogue loads: overlap with gather chain
  float di = dinv[node];
  uint4 sv = *(const uint4*)&t[(size_t)node * 128 + fl * 8];
  float4 bb0 = *(const float4*)&bias[fl * 8];
  float4 bb1 = *(const float4*)&bias[fl * 8 + 4];

  f32x2 acc2[4] = {};
  for (int base = e0; base < e1; base += 16) {
    int i0 = base + g, i1 = i0 + 4, i2 = i0 + 8, i3 = i0 + 12;
    int s0 = edges[i0 < e1 ? i0 : last];
    int s1 = edges[i1 < e1 ? i1 : last];
    int s2 = edges[i2 < e1 ? i2 : last];
    int s3 = edges[i3 < e1 ? i3 : last];
    s0 = i0 < e1 ? s0 : n;     // zero row
    s1 = i1 < e1 ? s1 : n;
    s2 = i2 < e1 ? s2 : n;
    s3 = i3 < e1 ? s3 : n;
    uint4 u0 = *(const uint4*)&t[(size_t)s0 * 128 + fl * 8];
    uint4 u1 = *(const uint4*)&t[(size_t)s1 * 128 + fl * 8];
    uint4 u2 = *(const uint4*)&t[(size_t)s2 * 128 + fl * 8];
    uint4 u3 = *(const uint4*)&t[(size_t)s3 * 128 + fl * 8];
    acc2[0] = pkadd(acc2[0], pkadd(pkadd(bfpair(u0.x), bfpair(u1.x)),
                                   pkadd(bfpair(u2.x), bfpair(u3.x))));
    acc2[1] = pkadd(acc2[1], pkadd(pkadd(bfpair(u0.y), bfpair(u1.y)),
                                   pkadd(bfpair(u2.y), bfpair(u3.y))));
    acc2[2] = pkadd(acc2[2], pkadd(pkadd(bfpair(u0.z), bfpair(u1.z)),
                                   pkadd(bfpair(u2.z), bfpair(u3.z))));
    acc2[3] = pkadd(acc2[3], pkadd(pkadd(bfpair(u0.w), bfpair(u1.w)),
                                   pkadd(bfpair(u2.w), bfpair(u3.w))));
  }
  float acc[8];
#pragma unroll
  for (int j = 0; j < 4; ++j) { acc[2 * j] = acc2[j].x; acc[2 * j + 1] = acc2[j].y; }
#pragma unroll
  for (int j = 0; j < 8; ++j) {
    acc[j] += __shfl_xor(acc[j], 16);
    acc[j] += __shfl_xor(acc[j], 32);
  }
  if (g == 0) {
    acc[0] += bf_lo(sv.x); acc[1] += bf_hi(sv.x);
    acc[2] += bf_lo(sv.y); acc[3] += bf_hi(sv.y);
    acc[4] += bf_lo(sv.z); acc[5] += bf_hi(sv.z);
    acc[6] += bf_lo(sv.w); acc[7] += bf_hi(sv.w);
    float bb[8] = {bb0.x, bb0.y, bb0.z, bb0.w, bb1.x, bb1.y, bb1.z, bb1.w};
    short8 ho, lo_;
#pragma unroll
    for (int j = 0; j < 8; ++j) {
      float s = fmaxf(acc[j] * di + bb[j], 0.f);
      __bf16 h = (__bf16)s;
      ho[j] = __builtin_bit_cast(short, h);
      lo_[j] = (short)f2bf(s - (float)h);
    }
    *(short8*)&ghi[(size_t)node * 128 + fl * 8] = ho;
    *(short8*)&glo[(size_t)node * 128 + fl * 8] = lo_;
  }
}

extern "C" void kernel_launch(void* const* d_in, const int* in_sizes, int n_in,
                              void* d_out, int out_size, void* d_ws, size_t ws_size,
                              hipStream_t stream) {
  const float* x  = (const float*)d_in[0];
  const int*   ei = (const int*)d_in[1];
  const float* W1 = (const float*)d_in[2];
  const float* b1 = (const float*)d_in[3];
  const float* W2 = (const float*)d_in[4];
  const float* b2 = (const float*)d_in[5];
  const float* Wl = (const float*)d_in[6];
  const float* bl = (const float*)d_in[7];
  float* out = (float*)d_out;

  const int D = 128;
  int N = in_sizes[0] / D;
  int E = in_sizes[1] / 2;
  const int* src = ei;
  const int* dst = ei + E;

  uintptr_t ws = (uintptr_t)d_ws;
  auto take = [&](size_t bytes) {
    uintptr_t p = ws;
    ws += (bytes + 15) & ~(size_t)15;
    return p;
  };
  unsigned short* t_bf = (unsigned short*)take(((size_t)N + 1) * D * 2);  // + zero row
  unsigned short* xh   = (unsigned short*)take((size_t)N * D * 2);
  unsigned short* xl   = (unsigned short*)take((size_t)N * D * 2);
  unsigned short* edges = (unsigned short*)take((size_t)E * 2);  // u16 src ids
  int*   rank    = (int*)take((size_t)E * 4);
  int*   cnt     = (int*)take((size_t)N * sizeof(int));
  int*   row_off = (int*)take(((size_t)N + 1) * sizeof(int));
  float* dinv    = (float*)take((size_t)N * sizeof(float));
  int*   partial = (int*)take(256 * sizeof(int));
  unsigned short* b1h = (unsigned short*)take(128 * 128 * 2);
  unsigned short* b1l = (unsigned short*)take(128 * 128 * 2);
  unsigned short* b2h = (unsigned short*)take(128 * 128 * 2);
  unsigned short* b2l = (unsigned short*)take(128 * 128 * 2);
  unsigned short* blh = (unsigned short*)take(128 * 64 * 2);
  unsigned short* bll = (unsigned short*)take(128 * 64 * 2);

  int nb_n = (N + 255) / 256;   // 196 (fits single-block base reduce)
  int nb_e = (E + 255) / 256;

  // ---- graph preprocessing + weight prep ----
  hipMemsetAsync(cnt, 0, (size_t)N * sizeof(int), stream);
  k_count_prepW<<<nb_e + 160, 256, 0, stream>>>(dst, E, nb_e, cnt, rank,
                                                W1, W2, Wl, b1h, b1l, b2h, b2l, blh, bll);
  k_scan1<<<nb_n, 256, 0, stream>>>(cnt, N, partial, dinv);
  k_scan3<<<nb_n, 256, 0, stream>>>(cnt, partial, nb_n, N, row_off);
  k_place<<<nb_e, 256, 0, stream>>>(src, dst, rank, row_off, E, edges);

  int gemm_blocks = (N + 127) / 128;
  int agg_blocks = (N + 3) / 4;

  // ---- layer 1 (A = fp32 x, split in-register; output pre-scaled by dinv) ----
  gemm3<8, true, false, true, true><<<gemm_blocks, 256, 0, stream>>>(
      x, nullptr, b1h, b1l, nullptr, dinv, t_bf, N);
  k_agg<<<agg_blocks, 256, 0, stream>>>(t_bf, row_off, edges, dinv, b1, xh, xl, N);
  // ---- layer 2 ----
  gemm3<8, false, false, true, true><<<gemm_blocks, 256, 0, stream>>>(
      xh, xl, b2h, b2l, nullptr, dinv, t_bf, N);
  k_agg<<<agg_blocks, 256, 0, stream>>>(t_bf, row_off, edges, dinv, b2, xh, xl, N);
  // ---- classifier ----
  gemm3<4, false, true, false, false><<<gemm_blocks, 256, 0, stream>>>(
      xh, xl, blh, bll, bl, nullptr, out, N);
}